// Round 1
// baseline (571.203 us; speedup 1.0000x reference)
//
#include <hip/hip_runtime.h>
#include <math.h>

#define BATCH 16
#define KVH   8
#define QM    4
#define HD    128
#define SLEN  4096

// ---------------------------------------------------------------------------
// Stage 1: flash-decode partials. grid (nseg/4, KVH, BATCH), block 256 (4 waves).
// Each wave owns segment seg = blockIdx.x*4 + wave, positions [seg*seglen, +seglen).
// Half-wave per position: lane = half*32 + comp, comp indexes float4 of the row.
// ---------------------------------------------------------------------------
__global__ __launch_bounds__(256) void attn_partial(
    const float* __restrict__ Q, const float* __restrict__ Kn,
    const float* __restrict__ Vn, const float* __restrict__ Kc,
    const float* __restrict__ Vc, const float* __restrict__ Mask,
    float* __restrict__ Op, float* __restrict__ Mp, float* __restrict__ Lp,
    int nseg, int seglen)
{
    const int tid  = threadIdx.x;
    const int wave = tid >> 6;
    const int lane = tid & 63;
    const int half = lane >> 5;
    const int comp = lane & 31;
    const int kv   = blockIdx.y;
    const int b    = blockIdx.z;
    const int seg  = blockIdx.x * 4 + wave;

    const float scale = 0.088388347648318447f;  // 1/sqrt(128)

    // Q for the 4 GQA heads of this kv head, pre-scaled. 4 floats per lane per head.
    const float* qb = Q + (size_t)b * (KVH * QM * HD) + kv * (QM * HD) + comp * 4;
    float4 q[QM];
#pragma unroll
    for (int h = 0; h < QM; ++h) {
        float4 t = *(const float4*)(qb + h * HD);
        q[h].x = t.x * scale; q[h].y = t.y * scale;
        q[h].z = t.z * scale; q[h].w = t.w * scale;
    }

    float  m = -INFINITY;           // joint running max (shared across 4 heads; arg of exp stays <= 0)
    float  l[QM] = {0.f, 0.f, 0.f, 0.f};
    float4 o[QM];
#pragma unroll
    for (int h = 0; h < QM; ++h) o[h] = make_float4(0.f, 0.f, 0.f, 0.f);

    const size_t rowstride = (size_t)KVH * HD;  // 1024 floats between cache positions
    const float* kc   = Kc + (size_t)b * SLEN * rowstride + kv * HD + comp * 4;
    const float* vc   = Vc + (size_t)b * SLEN * rowstride + kv * HD + comp * 4;
    const float* mrow = Mask + (size_t)b * SLEN;

    const int start = seg * seglen;
    const int niter = seglen >> 1;

    // register prefetch of the first pair
    int p = start + half;
    float4 kf = *(const float4*)(kc + (size_t)p * rowstride);
    float4 vf = *(const float4*)(vc + (size_t)p * rowstride);
    float  mk = mrow[p];

    for (int i = 0; i < niter; ++i) {
        // prefetch next pair (clamped re-read on the final iteration; discarded)
        int pn = start + 2 * (i + 1) + half;
        if (pn >= SLEN) pn = start + half;
        float4 kn2 = *(const float4*)(kc + (size_t)pn * rowstride);
        float4 vn2 = *(const float4*)(vc + (size_t)pn * rowstride);
        float  mkn = mrow[pn];

        // partial dot: 4 elements per lane, 4 heads
        float s[QM];
#pragma unroll
        for (int h = 0; h < QM; ++h)
            s[h] = q[h].x * kf.x + q[h].y * kf.y + q[h].z * kf.z + q[h].w * kf.w;
        // reduce across the 32-lane half (keeps the two positions separate)
#pragma unroll
        for (int off = 1; off <= 16; off <<= 1) {
#pragma unroll
            for (int h = 0; h < QM; ++h) s[h] += __shfl_xor(s[h], off);
        }
#pragma unroll
        for (int h = 0; h < QM; ++h) s[h] += mk;

        // joint max over 4 heads and both positions -> wave-uniform
        float mloc = fmaxf(fmaxf(s[0], s[1]), fmaxf(s[2], s[3]));
#pragma unroll
        for (int off = 1; off <= 32; off <<= 1)
            mloc = fmaxf(mloc, __shfl_xor(mloc, off));

        if (mloc > m) {                    // wave-uniform branch; rare after warm-up
            float alpha = __expf(m - mloc);
            m = mloc;
#pragma unroll
            for (int h = 0; h < QM; ++h) {
                l[h]   *= alpha;
                o[h].x *= alpha; o[h].y *= alpha; o[h].z *= alpha; o[h].w *= alpha;
            }
        }

        float w[QM];
#pragma unroll
        for (int h = 0; h < QM; ++h) { w[h] = __expf(s[h] - m); l[h] += w[h]; }
#pragma unroll
        for (int h = 0; h < QM; ++h) {
            o[h].x += w[h] * vf.x; o[h].y += w[h] * vf.y;
            o[h].z += w[h] * vf.z; o[h].w += w[h] * vf.w;
        }

        kf = kn2; vf = vn2; mk = mkn;
    }

    // tail: newly-appended token (position SLEN) handled by the last segment,
    // lower half only (upper half predicated to -inf weight)
    if (seg == nseg - 1) {
        const float* kp = Kn + (size_t)b * (KVH * HD) + kv * HD + comp * 4;
        const float* vp = Vn + (size_t)b * (KVH * HD) + kv * HD + comp * 4;
        float4 kt = *(const float4*)kp;
        float4 vt = *(const float4*)vp;
        float s[QM];
#pragma unroll
        for (int h = 0; h < QM; ++h)
            s[h] = q[h].x * kt.x + q[h].y * kt.y + q[h].z * kt.z + q[h].w * kt.w;
#pragma unroll
        for (int off = 1; off <= 16; off <<= 1) {
#pragma unroll
            for (int h = 0; h < QM; ++h) s[h] += __shfl_xor(s[h], off);
        }
        if (half != 0) {
#pragma unroll
            for (int h = 0; h < QM; ++h) s[h] = -INFINITY;
        }
        float mloc = fmaxf(fmaxf(s[0], s[1]), fmaxf(s[2], s[3]));
#pragma unroll
        for (int off = 1; off <= 32; off <<= 1)
            mloc = fmaxf(mloc, __shfl_xor(mloc, off));
        if (mloc > m) {
            float alpha = __expf(m - mloc);
            m = mloc;
#pragma unroll
            for (int h = 0; h < QM; ++h) {
                l[h]   *= alpha;
                o[h].x *= alpha; o[h].y *= alpha; o[h].z *= alpha; o[h].w *= alpha;
            }
        }
#pragma unroll
        for (int h = 0; h < QM; ++h) {
            float w = __expf(s[h] - m);    // 0 for the invalid upper half
            l[h] += w;
            o[h].x += w * vt.x; o[h].y += w * vt.y;
            o[h].z += w * vt.z; o[h].w += w * vt.w;
        }
    }

    // combine the two halves (xor-add is symmetric: both halves end with the sum)
#pragma unroll
    for (int h = 0; h < QM; ++h) {
        l[h]   += __shfl_xor(l[h], 32);
        o[h].x += __shfl_xor(o[h].x, 32);
        o[h].y += __shfl_xor(o[h].y, 32);
        o[h].z += __shfl_xor(o[h].z, 32);
        o[h].w += __shfl_xor(o[h].w, 32);
    }

    const size_t sidx = ((size_t)b * KVH + kv) * nseg + seg;
    if (lane == 0) {
#pragma unroll
        for (int h = 0; h < QM; ++h) { Mp[sidx * QM + h] = m; Lp[sidx * QM + h] = l[h]; }
    }
    if (half == 0) {
#pragma unroll
        for (int h = 0; h < QM; ++h)
            *(float4*)(Op + (sidx * QM + h) * HD + comp * 4) = o[h];
    }
}

// ---------------------------------------------------------------------------
// Stage 2: merge segment partials. grid BATCH*KVH blocks x HD threads.
// ---------------------------------------------------------------------------
__global__ __launch_bounds__(HD) void attn_combine(
    const float* __restrict__ Op, const float* __restrict__ Mp,
    const float* __restrict__ Lp, float* __restrict__ out, int nseg)
{
    const int d  = threadIdx.x;
    const int kv = blockIdx.x & (KVH - 1);
    const int b  = blockIdx.x / KVH;
    const size_t base = ((size_t)b * KVH + kv) * nseg;

    for (int h = 0; h < QM; ++h) {
        float M = -INFINITY;
        for (int c = 0; c < nseg; ++c)
            M = fmaxf(M, Mp[(base + c) * QM + h]);
        float L = 0.f, acc = 0.f;
        for (int c = 0; c < nseg; ++c) {
            float e = __expf(Mp[(base + c) * QM + h] - M);
            L   += Lp[(base + c) * QM + h] * e;
            acc += Op[((base + c) * QM + h) * HD + d] * e;
        }
        out[((size_t)b * KVH * QM + kv * QM + h) * HD + d] = acc / L;
    }
}

// ---------------------------------------------------------------------------
extern "C" void kernel_launch(void* const* d_in, const int* in_sizes, int n_in,
                              void* d_out, int out_size, void* d_ws, size_t ws_size,
                              hipStream_t stream)
{
    const float* Q    = (const float*)d_in[0];
    const float* K    = (const float*)d_in[1];
    const float* V    = (const float*)d_in[2];
    const float* Kc   = (const float*)d_in[3];
    const float* Vc   = (const float*)d_in[4];
    const float* Mask = (const float*)d_in[5];
    float* out = (float*)d_out;

    // pick segment count that fits the workspace: per-seg bytes = B*KV*QM*(HD+2)*4
    int nseg = 32;
    const size_t per_seg = (size_t)BATCH * KVH * QM * (HD + 2) * sizeof(float);
    while (nseg > 4 && (size_t)nseg * per_seg > ws_size) nseg >>= 1;
    const int seglen = SLEN / nseg;

    float* Op = (float*)d_ws;
    float* Mp = Op + (size_t)nseg * BATCH * KVH * QM * HD;
    float* Lp = Mp + (size_t)nseg * BATCH * KVH * QM;

    dim3 grid1(nseg / 4, KVH, BATCH);
    attn_partial<<<grid1, 256, 0, stream>>>(Q, K, V, Kc, Vc, Mask, Op, Mp, Lp, nseg, seglen);
    attn_combine<<<dim3(BATCH * KVH), HD, 0, stream>>>(Op, Mp, Lp, out, nseg);
}

// Round 2
// 556.027 us; speedup vs baseline: 1.0273x; 1.0273x over previous
//
#include <hip/hip_runtime.h>
#include <math.h>

#define BATCH 16
#define KVH   8
#define QM    4
#define HD    128
#define SLEN  4096

// ---------------------------------------------------------------------------
// Stage 1: flash-decode partials, fixed-max (m=0) softmax.
//   grid (nseg/4, KVH, BATCH), block 256 (4 waves, one segment per wave).
//   Lane layout: g = lane>>4 (position group, 4 positions/iter),
//                c = lane&15 (16 lanes per position).
//   Chunk j in {0,1}: element d = j*64 + c*4 .. +4  (each load instruction
//   covers 256 contiguous bytes per position -> full cache lines).
//   Scores are bounded (|s| <= |Q||K|/sqrt(128) ~ 11.3) so exp without max
//   subtraction cannot overflow fp32; partials combine by plain summation.
// ---------------------------------------------------------------------------
__global__ __launch_bounds__(256, 4) void attn_partial(
    const float* __restrict__ Q, const float* __restrict__ Kn,
    const float* __restrict__ Vn, const float* __restrict__ Kc,
    const float* __restrict__ Vc, const float* __restrict__ Mask,
    float* __restrict__ Op, float* __restrict__ Lp,
    int nseg, int seglen)
{
    const int tid  = threadIdx.x;
    const int wave = tid >> 6;
    const int lane = tid & 63;
    const int g    = lane >> 4;    // position group 0..3
    const int c    = lane & 15;    // 16 lanes per position
    const int kv   = blockIdx.y;
    const int b    = blockIdx.z;
    const int seg  = blockIdx.x * 4 + wave;

    const float scale = 0.088388347648318447f;  // 1/sqrt(128)

    // Q fragments for the 4 GQA heads, pre-scaled. d = j*64 + c*4.
    const float* qb = Q + (size_t)b * (KVH * QM * HD) + kv * (QM * HD) + c * 4;
    float4 q[QM][2];
#pragma unroll
    for (int h = 0; h < QM; ++h) {
#pragma unroll
        for (int j = 0; j < 2; ++j) {
            float4 t = *(const float4*)(qb + h * HD + j * 64);
            q[h][j].x = t.x * scale; q[h][j].y = t.y * scale;
            q[h][j].z = t.z * scale; q[h][j].w = t.w * scale;
        }
    }

    float  l[QM] = {0.f, 0.f, 0.f, 0.f};
    float4 o[QM][2];
#pragma unroll
    for (int h = 0; h < QM; ++h)
#pragma unroll
        for (int j = 0; j < 2; ++j) o[h][j] = make_float4(0.f, 0.f, 0.f, 0.f);

    const size_t rowstride = (size_t)KVH * HD;  // floats between positions
    const float* kc   = Kc + (size_t)b * SLEN * rowstride + kv * HD + c * 4;
    const float* vc   = Vc + (size_t)b * SLEN * rowstride + kv * HD + c * 4;
    const float* mrow = Mask + (size_t)b * SLEN;

    const int start = seg * seglen;
    const int niter = seglen >> 2;   // 4 positions per iteration

    for (int i = 0; i < niter; ++i) {
        const int pos = start + i * 4 + g;
        const float* kp = kc + (size_t)pos * rowstride;
        const float* vp = vc + (size_t)pos * rowstride;
        float4 k0 = *(const float4*)(kp);
        float4 k1 = *(const float4*)(kp + 64);
        float4 v0 = *(const float4*)(vp);
        float4 v1 = *(const float4*)(vp + 64);
        float  mk = mrow[pos];

        float s[QM];
#pragma unroll
        for (int h = 0; h < QM; ++h)
            s[h] = q[h][0].x * k0.x + q[h][0].y * k0.y + q[h][0].z * k0.z + q[h][0].w * k0.w
                 + q[h][1].x * k1.x + q[h][1].y * k1.y + q[h][1].z * k1.z + q[h][1].w * k1.w;

        // reduce across the 16 lanes of this position (4 dependent levels)
#pragma unroll
        for (int off = 1; off <= 8; off <<= 1) {
#pragma unroll
            for (int h = 0; h < QM; ++h) s[h] += __shfl_xor(s[h], off);
        }

#pragma unroll
        for (int h = 0; h < QM; ++h) {
            float w = __expf(s[h] + mk);   // fixed max = 0; cannot overflow (|s|<=~11.3)
            l[h] += w;
            o[h][0].x += w * v0.x; o[h][0].y += w * v0.y;
            o[h][0].z += w * v0.z; o[h][0].w += w * v0.w;
            o[h][1].x += w * v1.x; o[h][1].y += w * v1.y;
            o[h][1].z += w * v1.z; o[h][1].w += w * v1.w;
        }
    }

    // tail: newly-appended token (position SLEN), mask pad = 0.
    // All groups compute it; only group 0's contribution is kept.
    if (seg == nseg - 1) {
        const float* kp = Kn + (size_t)b * (KVH * HD) + kv * HD + c * 4;
        const float* vp = Vn + (size_t)b * (KVH * HD) + kv * HD + c * 4;
        float4 k0 = *(const float4*)(kp);
        float4 k1 = *(const float4*)(kp + 64);
        float4 v0 = *(const float4*)(vp);
        float4 v1 = *(const float4*)(vp + 64);
        float s[QM];
#pragma unroll
        for (int h = 0; h < QM; ++h)
            s[h] = q[h][0].x * k0.x + q[h][0].y * k0.y + q[h][0].z * k0.z + q[h][0].w * k0.w
                 + q[h][1].x * k1.x + q[h][1].y * k1.y + q[h][1].z * k1.z + q[h][1].w * k1.w;
#pragma unroll
        for (int off = 1; off <= 8; off <<= 1) {
#pragma unroll
            for (int h = 0; h < QM; ++h) s[h] += __shfl_xor(s[h], off);
        }
        const float gate = (g == 0) ? 1.f : 0.f;
#pragma unroll
        for (int h = 0; h < QM; ++h) {
            float w = __expf(s[h]) * gate;
            l[h] += w;
            o[h][0].x += w * v0.x; o[h][0].y += w * v0.y;
            o[h][0].z += w * v0.z; o[h][0].w += w * v0.w;
            o[h][1].x += w * v1.x; o[h][1].y += w * v1.y;
            o[h][1].z += w * v1.z; o[h][1].w += w * v1.w;
        }
    }

    // combine the 4 position groups (2 dependent levels, once per segment)
    float* ov = (float*)o;   // 32 floats
#pragma unroll
    for (int off = 16; off <= 32; off <<= 1) {
#pragma unroll
        for (int h = 0; h < QM; ++h) l[h] += __shfl_xor(l[h], off);
#pragma unroll
        for (int i = 0; i < QM * 8; ++i) ov[i] += __shfl_xor(ov[i], off);
    }

    // write-out: group g writes head g (all groups hold identical sums now)
    const size_t sidx = ((size_t)b * KVH + kv) * nseg + seg;
    float* op = Op + (sidx * QM + g) * HD + c * 4;
    *(float4*)(op)      = o[g][0];
    *(float4*)(op + 64) = o[g][1];
    if (c == 0) Lp[sidx * QM + g] = l[g];
}

// ---------------------------------------------------------------------------
// Stage 2: plain-sum merge (fixed max). grid BATCH*KVH*QM blocks x HD threads.
// ---------------------------------------------------------------------------
__global__ __launch_bounds__(HD) void attn_combine(
    const float* __restrict__ Op, const float* __restrict__ Lp,
    float* __restrict__ out, int nseg)
{
    const int d  = threadIdx.x;
    const int h  = blockIdx.x & (QM - 1);
    const int kv = (blockIdx.x >> 2) & (KVH - 1);
    const int b  = blockIdx.x >> 5;
    const size_t base = ((size_t)b * KVH + kv) * nseg;

    float acc = 0.f, L = 0.f;
    for (int cseg = 0; cseg < nseg; ++cseg) {
        acc += Op[(base + cseg) * QM * HD + h * HD + d];
        L   += Lp[(base + cseg) * QM + h];
    }
    out[((size_t)b * KVH * QM + kv * QM + h) * HD + d] = acc / L;
}

// ---------------------------------------------------------------------------
extern "C" void kernel_launch(void* const* d_in, const int* in_sizes, int n_in,
                              void* d_out, int out_size, void* d_ws, size_t ws_size,
                              hipStream_t stream)
{
    const float* Q    = (const float*)d_in[0];
    const float* K    = (const float*)d_in[1];
    const float* V    = (const float*)d_in[2];
    const float* Kc   = (const float*)d_in[3];
    const float* Vc   = (const float*)d_in[4];
    const float* Mask = (const float*)d_in[5];
    float* out = (float*)d_out;

    // segment count fitting workspace: per-seg = B*KV*QM*(HD+1)*4 bytes
    int nseg = 32;
    const size_t per_seg = (size_t)BATCH * KVH * QM * (HD + 1) * sizeof(float);
    while (nseg > 4 && (size_t)nseg * per_seg > ws_size) nseg >>= 1;
    const int seglen = SLEN / nseg;

    float* Op = (float*)d_ws;
    float* Lp = Op + (size_t)nseg * BATCH * KVH * QM * HD;

    dim3 grid1(nseg / 4, KVH, BATCH);
    attn_partial<<<grid1, 256, 0, stream>>>(Q, K, V, Kc, Vc, Mask, Op, Lp, nseg, seglen);
    attn_combine<<<dim3(BATCH * KVH * QM), HD, 0, stream>>>(Op, Lp, out, nseg);
}

// Round 3
// 547.411 us; speedup vs baseline: 1.0435x; 1.0157x over previous
//
#include <hip/hip_runtime.h>
#include <math.h>

#define BATCH 16
#define KVH   8
#define QM    4
#define HD    128
#define SLEN  4096

// ---------------------------------------------------------------------------
// Stage 1: flash-decode partials, fixed-max (m=0) softmax.
//   grid (nseg/4, KVH, BATCH), block 256 (4 waves, one segment per wave).
//   Lane layout: g = lane>>4 (position group, 4 positions/iter),
//                c = lane&15 (16 lanes per position).
//   NOTE: every register-array index is a compile-time constant (full unroll,
//   no pointer casts) -- runtime indexing forced the accumulators to scratch
//   in R2 (WRITE_SIZE 8->76 MB, VGPR_Count 60).
//   Scores are bounded (|s| <= |Q||K|/sqrt(128) ~ 11) so exp with fixed max 0
//   cannot overflow fp32; partials combine by plain summation in stage 2.
// ---------------------------------------------------------------------------
__global__ __launch_bounds__(256, 4) void attn_partial(
    const float* __restrict__ Q, const float* __restrict__ Kn,
    const float* __restrict__ Vn, const float* __restrict__ Kc,
    const float* __restrict__ Vc, const float* __restrict__ Mask,
    float* __restrict__ Op, float* __restrict__ Lp,
    int nseg, int seglen)
{
    const int tid  = threadIdx.x;
    const int wave = tid >> 6;
    const int lane = tid & 63;
    const int g    = lane >> 4;    // position group 0..3
    const int c    = lane & 15;    // 16 lanes per position
    const int kv   = blockIdx.y;
    const int b    = blockIdx.z;
    const int seg  = blockIdx.x * 4 + wave;

    const float scale = 0.088388347648318447f;  // 1/sqrt(128)

    // Q fragments for the 4 GQA heads, pre-scaled. element d = j*64 + c*4.
    const float* qb = Q + (size_t)b * (KVH * QM * HD) + kv * (QM * HD) + c * 4;
    float4 q[QM][2];
#pragma unroll
    for (int h = 0; h < QM; ++h) {
#pragma unroll
        for (int j = 0; j < 2; ++j) {
            float4 t = *(const float4*)(qb + h * HD + j * 64);
            q[h][j].x = t.x * scale; q[h][j].y = t.y * scale;
            q[h][j].z = t.z * scale; q[h][j].w = t.w * scale;
        }
    }

    float  l[QM] = {0.f, 0.f, 0.f, 0.f};
    float4 o[QM][2];
#pragma unroll
    for (int h = 0; h < QM; ++h)
#pragma unroll
        for (int j = 0; j < 2; ++j) o[h][j] = make_float4(0.f, 0.f, 0.f, 0.f);

    const size_t rowstride = (size_t)KVH * HD;  // floats between cache positions
    const float* kc   = Kc + (size_t)b * SLEN * rowstride + kv * HD + c * 4;
    const float* vc   = Vc + (size_t)b * SLEN * rowstride + kv * HD + c * 4;
    const float* mrow = Mask + (size_t)b * SLEN;

    const int start = seg * seglen;
    const int niter = seglen >> 2;   // 4 positions per iteration

    for (int i = 0; i < niter; ++i) {
        const int pos = start + i * 4 + g;
        const float* kp = kc + (size_t)pos * rowstride;
        const float* vp = vc + (size_t)pos * rowstride;
        float4 k0 = *(const float4*)(kp);
        float4 k1 = *(const float4*)(kp + 64);
        float4 v0 = *(const float4*)(vp);
        float4 v1 = *(const float4*)(vp + 64);
        float  mk = mrow[pos];

        float s[QM];
#pragma unroll
        for (int h = 0; h < QM; ++h)
            s[h] = q[h][0].x * k0.x + q[h][0].y * k0.y + q[h][0].z * k0.z + q[h][0].w * k0.w
                 + q[h][1].x * k1.x + q[h][1].y * k1.y + q[h][1].z * k1.z + q[h][1].w * k1.w;

        // reduce across the 16 lanes of this position (4 dependent levels)
#pragma unroll
        for (int off = 1; off <= 8; off <<= 1) {
#pragma unroll
            for (int h = 0; h < QM; ++h) s[h] += __shfl_xor(s[h], off);
        }

#pragma unroll
        for (int h = 0; h < QM; ++h) {
            float w = __expf(s[h] + mk);   // fixed max = 0
            l[h] += w;
            o[h][0].x += w * v0.x; o[h][0].y += w * v0.y;
            o[h][0].z += w * v0.z; o[h][0].w += w * v0.w;
            o[h][1].x += w * v1.x; o[h][1].y += w * v1.y;
            o[h][1].z += w * v1.z; o[h][1].w += w * v1.w;
        }
    }

    // tail: newly-appended token (position SLEN), mask pad = 0.
    // All groups compute it; only group 0's contribution is kept (gate).
    if (seg == nseg - 1) {
        const float* kp = Kn + (size_t)b * (KVH * HD) + kv * HD + c * 4;
        const float* vp = Vn + (size_t)b * (KVH * HD) + kv * HD + c * 4;
        float4 k0 = *(const float4*)(kp);
        float4 k1 = *(const float4*)(kp + 64);
        float4 v0 = *(const float4*)(vp);
        float4 v1 = *(const float4*)(vp + 64);
        float s[QM];
#pragma unroll
        for (int h = 0; h < QM; ++h)
            s[h] = q[h][0].x * k0.x + q[h][0].y * k0.y + q[h][0].z * k0.z + q[h][0].w * k0.w
                 + q[h][1].x * k1.x + q[h][1].y * k1.y + q[h][1].z * k1.z + q[h][1].w * k1.w;
#pragma unroll
        for (int off = 1; off <= 8; off <<= 1) {
#pragma unroll
            for (int h = 0; h < QM; ++h) s[h] += __shfl_xor(s[h], off);
        }
        const float gate = (g == 0) ? 1.f : 0.f;
#pragma unroll
        for (int h = 0; h < QM; ++h) {
            float w = __expf(s[h]) * gate;
            l[h] += w;
            o[h][0].x += w * v0.x; o[h][0].y += w * v0.y;
            o[h][0].z += w * v0.z; o[h][0].w += w * v0.w;
            o[h][1].x += w * v1.x; o[h][1].y += w * v1.y;
            o[h][1].z += w * v1.z; o[h][1].w += w * v1.w;
        }
    }

    // combine the 4 position groups: 2 symmetric xor levels, all indices const.
#pragma unroll
    for (int off = 16; off <= 32; off <<= 1) {
#pragma unroll
        for (int h = 0; h < QM; ++h) {
            l[h]      += __shfl_xor(l[h],      off);
            o[h][0].x += __shfl_xor(o[h][0].x, off);
            o[h][0].y += __shfl_xor(o[h][0].y, off);
            o[h][0].z += __shfl_xor(o[h][0].z, off);
            o[h][0].w += __shfl_xor(o[h][0].w, off);
            o[h][1].x += __shfl_xor(o[h][1].x, off);
            o[h][1].y += __shfl_xor(o[h][1].y, off);
            o[h][1].z += __shfl_xor(o[h][1].z, off);
            o[h][1].w += __shfl_xor(o[h][1].w, off);
        }
    }

    // write-out: group 0 writes all 4 heads (constant h indices; all lanes
    // hold identical sums after the symmetric reduction). Once per segment.
    const size_t sidx = ((size_t)b * KVH + kv) * nseg + seg;
    if (g == 0) {
#pragma unroll
        for (int h = 0; h < QM; ++h) {
            float* op = Op + (sidx * QM + h) * HD + c * 4;
            *(float4*)(op)      = o[h][0];
            *(float4*)(op + 64) = o[h][1];
            if (c == 0) Lp[sidx * QM + h] = l[h];
        }
    }
}

// ---------------------------------------------------------------------------
// Stage 2: plain-sum merge (fixed max). grid BATCH*KVH*QM blocks x HD threads.
// ---------------------------------------------------------------------------
__global__ __launch_bounds__(HD) void attn_combine(
    const float* __restrict__ Op, const float* __restrict__ Lp,
    float* __restrict__ out, int nseg)
{
    const int d  = threadIdx.x;
    const int h  = blockIdx.x & (QM - 1);
    const int kv = (blockIdx.x >> 2) & (KVH - 1);
    const int b  = blockIdx.x >> 5;
    const size_t base = ((size_t)b * KVH + kv) * nseg;

    float acc = 0.f, L = 0.f;
    for (int cseg = 0; cseg < nseg; ++cseg) {
        acc += Op[(base + cseg) * QM * HD + h * HD + d];
        L   += Lp[(base + cseg) * QM + h];
    }
    out[((size_t)b * KVH * QM + kv * QM + h) * HD + d] = acc / L;
}

// ---------------------------------------------------------------------------
extern "C" void kernel_launch(void* const* d_in, const int* in_sizes, int n_in,
                              void* d_out, int out_size, void* d_ws, size_t ws_size,
                              hipStream_t stream)
{
    const float* Q    = (const float*)d_in[0];
    const float* K    = (const float*)d_in[1];
    const float* V    = (const float*)d_in[2];
    const float* Kc   = (const float*)d_in[3];
    const float* Vc   = (const float*)d_in[4];
    const float* Mask = (const float*)d_in[5];
    float* out = (float*)d_out;

    // nseg=64 -> 2048 blocks -> 8192 waves = 100% wave-slot fill.
    // auto-shrink if workspace is too small: per-seg = B*KV*QM*(HD+1)*4 bytes
    int nseg = 64;
    const size_t per_seg = (size_t)BATCH * KVH * QM * (HD + 1) * sizeof(float);
    while (nseg > 4 && (size_t)nseg * per_seg > ws_size) nseg >>= 1;
    const int seglen = SLEN / nseg;

    float* Op = (float*)d_ws;
    float* Lp = Op + (size_t)nseg * BATCH * KVH * QM * HD;

    dim3 grid1(nseg / 4, KVH, BATCH);
    attn_partial<<<grid1, 256, 0, stream>>>(Q, K, V, Kc, Vc, Mask, Op, Lp, nseg, seglen);
    attn_combine<<<dim3(BATCH * KVH * QM), HD, 0, stream>>>(Op, Lp, out, nseg);
}

// Round 4
// 545.224 us; speedup vs baseline: 1.0476x; 1.0040x over previous
//
#include <hip/hip_runtime.h>
#include <math.h>

#define BATCH 16
#define KVH   8
#define QM    4
#define HD    128
#define SLEN  4096

// ---------------------------------------------------------------------------
// Stage 1: flash-decode partials, fixed-max (m=0) softmax, software-pipelined.
//   grid (nseg/4, KVH, BATCH), block 256 (4 waves, one segment per wave).
//   Lane layout: g = lane>>4 (position group), c = lane&15.
//   Each group handles 2 adjacent positions per iteration (8/wave-iter).
//   Pipeline: K(+mask) for iter i+1 is register-prefetched during iter i;
//   V for iter i is loaded at the top of iter i and its latency hides under
//   the dot + 4-level swizzle reduce + exp of the (already-resident) K.
//   All register arrays are fully unrolled / constant-indexed (R2 lesson:
//   runtime indices -> scratch, WRITE_SIZE 8->76MB).
//   Scores bounded (|s| <= ~11) so exp with fixed max 0 is safe in fp32;
//   stage-2 merge is a plain sum.
// ---------------------------------------------------------------------------
__global__ __launch_bounds__(256, 3) void attn_partial(
    const float* __restrict__ Q, const float* __restrict__ Kn,
    const float* __restrict__ Vn, const float* __restrict__ Kc,
    const float* __restrict__ Vc, const float* __restrict__ Mask,
    float* __restrict__ Op, float* __restrict__ Lp,
    int nseg, int seglen)
{
    const int tid  = threadIdx.x;
    const int wave = tid >> 6;
    const int lane = tid & 63;
    const int g    = lane >> 4;    // position group 0..3
    const int c    = lane & 15;    // 16 lanes per position
    const int kv   = blockIdx.y;
    const int b    = blockIdx.z;
    const int seg  = blockIdx.x * 4 + wave;

    const float scale = 0.088388347648318447f;  // 1/sqrt(128)

    // Q fragments for the 4 GQA heads, pre-scaled. element d = j*64 + c*4.
    const float* qb = Q + (size_t)b * (KVH * QM * HD) + kv * (QM * HD) + c * 4;
    float4 q[QM][2];
#pragma unroll
    for (int h = 0; h < QM; ++h) {
#pragma unroll
        for (int j = 0; j < 2; ++j) {
            float4 t = *(const float4*)(qb + h * HD + j * 64);
            q[h][j].x = t.x * scale; q[h][j].y = t.y * scale;
            q[h][j].z = t.z * scale; q[h][j].w = t.w * scale;
        }
    }

    float  l[QM] = {0.f, 0.f, 0.f, 0.f};
    float4 o[QM][2];
#pragma unroll
    for (int h = 0; h < QM; ++h)
#pragma unroll
        for (int j = 0; j < 2; ++j) o[h][j] = make_float4(0.f, 0.f, 0.f, 0.f);

    const size_t rowstride = (size_t)KVH * HD;  // floats between cache positions
    const float* kc   = Kc + (size_t)b * SLEN * rowstride + kv * HD + c * 4;
    const float* vc   = Vc + (size_t)b * SLEN * rowstride + kv * HD + c * 4;
    const float* mrow = Mask + (size_t)b * SLEN;

    const int start = seg * seglen;
    const int niter = seglen >> 3;   // 8 positions per iteration (2 per group)

    // --- prefetch K + mask for the first position pair of this group ---
    int pA = start + g * 2;
    const float* kpA = kc + (size_t)pA * rowstride;
    const float* kpB = kpA + rowstride;
    float4 ka0 = *(const float4*)(kpA);
    float4 ka1 = *(const float4*)(kpA + 64);
    float4 kb0 = *(const float4*)(kpB);
    float4 kb1 = *(const float4*)(kpB + 64);
    float  ma  = mrow[pA];
    float  mb  = mrow[pA + 1];

    for (int i = 0; i < niter; ++i) {
        const int pos = start + i * 8 + g * 2;

        // V for the current pair: issued first, consumed last (latency hidden
        // under dot + swizzle reduce + exp on the prefetched K).
        const float* vpA = vc + (size_t)pos * rowstride;
        const float* vpB = vpA + rowstride;
        float4 va0 = *(const float4*)(vpA);
        float4 va1 = *(const float4*)(vpA + 64);
        float4 vb0 = *(const float4*)(vpB);
        float4 vb1 = *(const float4*)(vpB + 64);

        // K + mask prefetch for the next pair (clamped dummy on last iter).
        int pn = pos + 8;
        if (i + 1 == niter) pn = start + g * 2;
        const float* kpAn = kc + (size_t)pn * rowstride;
        const float* kpBn = kpAn + rowstride;
        float4 nka0 = *(const float4*)(kpAn);
        float4 nka1 = *(const float4*)(kpAn + 64);
        float4 nkb0 = *(const float4*)(kpBn);
        float4 nkb1 = *(const float4*)(kpBn + 64);
        float  nma  = mrow[pn];
        float  nmb  = mrow[pn + 1];

        // dots for both positions, 4 heads each (K already in registers)
        float sA[QM], sB[QM];
#pragma unroll
        for (int h = 0; h < QM; ++h) {
            sA[h] = q[h][0].x * ka0.x + q[h][0].y * ka0.y + q[h][0].z * ka0.z + q[h][0].w * ka0.w
                  + q[h][1].x * ka1.x + q[h][1].y * ka1.y + q[h][1].z * ka1.z + q[h][1].w * ka1.w;
            sB[h] = q[h][0].x * kb0.x + q[h][0].y * kb0.y + q[h][0].z * kb0.z + q[h][0].w * kb0.w
                  + q[h][1].x * kb1.x + q[h][1].y * kb1.y + q[h][1].z * kb1.z + q[h][1].w * kb1.w;
        }
        // reduce across the 16 lanes (4 dependent levels; 8 independent values
        // per level keep the DS pipe fed)
#pragma unroll
        for (int off = 1; off <= 8; off <<= 1) {
#pragma unroll
            for (int h = 0; h < QM; ++h) {
                sA[h] += __shfl_xor(sA[h], off);
                sB[h] += __shfl_xor(sB[h], off);
            }
        }

#pragma unroll
        for (int h = 0; h < QM; ++h) {
            float wA = __expf(sA[h] + ma);   // fixed max = 0
            float wB = __expf(sB[h] + mb);
            l[h] += wA + wB;
            o[h][0].x += wA * va0.x + wB * vb0.x;
            o[h][0].y += wA * va0.y + wB * vb0.y;
            o[h][0].z += wA * va0.z + wB * vb0.z;
            o[h][0].w += wA * va0.w + wB * vb0.w;
            o[h][1].x += wA * va1.x + wB * vb1.x;
            o[h][1].y += wA * va1.y + wB * vb1.y;
            o[h][1].z += wA * va1.z + wB * vb1.z;
            o[h][1].w += wA * va1.w + wB * vb1.w;
        }

        ka0 = nka0; ka1 = nka1; kb0 = nkb0; kb1 = nkb1;
        ma = nma; mb = nmb;
    }

    // tail: newly-appended token (position SLEN), mask pad = 0.
    // All groups compute it; only group 0's contribution is kept (gate).
    if (seg == nseg - 1) {
        const float* kp = Kn + (size_t)b * (KVH * HD) + kv * HD + c * 4;
        const float* vp = Vn + (size_t)b * (KVH * HD) + kv * HD + c * 4;
        float4 k0 = *(const float4*)(kp);
        float4 k1 = *(const float4*)(kp + 64);
        float4 v0 = *(const float4*)(vp);
        float4 v1 = *(const float4*)(vp + 64);
        float s[QM];
#pragma unroll
        for (int h = 0; h < QM; ++h)
            s[h] = q[h][0].x * k0.x + q[h][0].y * k0.y + q[h][0].z * k0.z + q[h][0].w * k0.w
                 + q[h][1].x * k1.x + q[h][1].y * k1.y + q[h][1].z * k1.z + q[h][1].w * k1.w;
#pragma unroll
        for (int off = 1; off <= 8; off <<= 1) {
#pragma unroll
            for (int h = 0; h < QM; ++h) s[h] += __shfl_xor(s[h], off);
        }
        const float gate = (g == 0) ? 1.f : 0.f;
#pragma unroll
        for (int h = 0; h < QM; ++h) {
            float w = __expf(s[h]) * gate;
            l[h] += w;
            o[h][0].x += w * v0.x; o[h][0].y += w * v0.y;
            o[h][0].z += w * v0.z; o[h][0].w += w * v0.w;
            o[h][1].x += w * v1.x; o[h][1].y += w * v1.y;
            o[h][1].z += w * v1.z; o[h][1].w += w * v1.w;
        }
    }

    // combine the 4 position groups: 2 symmetric xor levels, constant indices.
#pragma unroll
    for (int off = 16; off <= 32; off <<= 1) {
#pragma unroll
        for (int h = 0; h < QM; ++h) {
            l[h]      += __shfl_xor(l[h],      off);
            o[h][0].x += __shfl_xor(o[h][0].x, off);
            o[h][0].y += __shfl_xor(o[h][0].y, off);
            o[h][0].z += __shfl_xor(o[h][0].z, off);
            o[h][0].w += __shfl_xor(o[h][0].w, off);
            o[h][1].x += __shfl_xor(o[h][1].x, off);
            o[h][1].y += __shfl_xor(o[h][1].y, off);
            o[h][1].z += __shfl_xor(o[h][1].z, off);
            o[h][1].w += __shfl_xor(o[h][1].w, off);
        }
    }

    // write-out: group 0 writes all 4 heads (constant h indices).
    const size_t sidx = ((size_t)b * KVH + kv) * nseg + seg;
    if (g == 0) {
#pragma unroll
        for (int h = 0; h < QM; ++h) {
            float* op = Op + (sidx * QM + h) * HD + c * 4;
            *(float4*)(op)      = o[h][0];
            *(float4*)(op + 64) = o[h][1];
            if (c == 0) Lp[sidx * QM + h] = l[h];
        }
    }
}

// ---------------------------------------------------------------------------
// Stage 2: plain-sum merge (fixed max). grid BATCH*KVH*QM blocks x HD threads.
// ---------------------------------------------------------------------------
__global__ __launch_bounds__(HD) void attn_combine(
    const float* __restrict__ Op, const float* __restrict__ Lp,
    float* __restrict__ out, int nseg)
{
    const int d  = threadIdx.x;
    const int h  = blockIdx.x & (QM - 1);
    const int kv = (blockIdx.x >> 2) & (KVH - 1);
    const int b  = blockIdx.x >> 5;
    const size_t base = ((size_t)b * KVH + kv) * nseg;

    float acc = 0.f, L = 0.f;
    for (int cseg = 0; cseg < nseg; ++cseg) {
        acc += Op[(base + cseg) * QM * HD + h * HD + d];
        L   += Lp[(base + cseg) * QM + h];
    }
    out[((size_t)b * KVH * QM + kv * QM + h) * HD + d] = acc / L;
}

// ---------------------------------------------------------------------------
extern "C" void kernel_launch(void* const* d_in, const int* in_sizes, int n_in,
                              void* d_out, int out_size, void* d_ws, size_t ws_size,
                              hipStream_t stream)
{
    const float* Q    = (const float*)d_in[0];
    const float* K    = (const float*)d_in[1];
    const float* V    = (const float*)d_in[2];
    const float* Kc   = (const float*)d_in[3];
    const float* Vc   = (const float*)d_in[4];
    const float* Mask = (const float*)d_in[5];
    float* out = (float*)d_out;

    // nseg=64 -> 2048 blocks. auto-shrink if workspace is too small.
    int nseg = 64;
    const size_t per_seg = (size_t)BATCH * KVH * QM * (HD + 1) * sizeof(float);
    while (nseg > 8 && (size_t)nseg * per_seg > ws_size) nseg >>= 1;
    const int seglen = SLEN / nseg;

    float* Op = (float*)d_ws;
    float* Lp = Op + (size_t)nseg * BATCH * KVH * QM * HD;

    dim3 grid1(nseg / 4, KVH, BATCH);
    attn_partial<<<grid1, 256, 0, stream>>>(Q, K, V, Kc, Vc, Mask, Op, Lp, nseg, seglen);
    attn_combine<<<dim3(BATCH * KVH * QM), HD, 0, stream>>>(Op, Lp, out, nseg);
}